// Round 1
// baseline (544.790 us; speedup 1.0000x reference)
//
#include <hip/hip_runtime.h>

// GraphAttention fused forward for MI355X (gfx950).
// B=4, N=2048, F=64, FP=32, H=4.  Output: [B,N,H*FP] f32 ++ uloss ++ eloss.

#define B_ 4
#define N_ 2048
#define F_ 64
#define FP_ 32
#define H_ 4
#define C_ (H_ * FP_)          // 128
#define JC_ 8                  // j-chunks per row (additive partials)
#define JSPAN_ (N_ / JC_)      // 256
#define PREC_ 36               // floats per partial record (32 acc + l + A + nz + pad)

// ---------------------------------------------------------------- kernel 1
// feats[b,h,n,d] = sum_f x[b,n,f] * W[h,f,d];  s = feats . a_self; t = feats . a_neigh
__global__ __launch_bounds__(128) void prep_kernel(
    const float* __restrict__ x, const float* __restrict__ W,
    const float* __restrict__ a_self, const float* __restrict__ a_neigh,
    float* __restrict__ feats, float* __restrict__ sbuf, float* __restrict__ tbuf)
{
    int bn = blockIdx.x;              // b*N + n
    __shared__ float xs[F_];
    int t = threadIdx.x;
    if (t < F_) xs[t] = x[(size_t)bn * F_ + t];
    __syncthreads();
    int h = t >> 5, d = t & 31;
    const float* Wh = W + (size_t)h * F_ * FP_ + d;
    float acc = 0.f;
#pragma unroll
    for (int f = 0; f < F_; ++f) acc += xs[f] * Wh[(size_t)f * FP_];
    int b = bn >> 11, n = bn & (N_ - 1);
    size_t row = ((size_t)b * H_ + h) * N_ + n;
    feats[row * FP_ + d] = acc;
    float sv = acc * a_self[h * FP_ + d];
    float tv = acc * a_neigh[h * FP_ + d];
#pragma unroll
    for (int o = 16; o; o >>= 1) {
        sv += __shfl_down(sv, o, 32);
        tv += __shfl_down(tv, o, 32);
    }
    if (d == 0) { sbuf[row] = sv; tbuf[row] = tv; }
}

// ---------------------------------------------------------------- kernel 2
// One wave per (b, h, 64-row i-group, j-chunk). Lanes = i rows, j loop uniform.
// No-max softmax: partials are additive across j-chunks.
__global__ __launch_bounds__(256) void attn_kernel(
    const float* __restrict__ adj, const float* __restrict__ attn_mask,
    const float* __restrict__ feats, const float* __restrict__ sbuf,
    const float* __restrict__ tbuf, float* __restrict__ part)
{
    int w = (blockIdx.x << 2) + (threadIdx.x >> 6);   // global wave id, 0..4095
    int lane = threadIdx.x & 63;
    int jc = w & (JC_ - 1);
    int rest = w >> 3;
    int ig = rest & 31; rest >>= 5;                   // N/64 = 32 groups
    int h = rest & (H_ - 1);
    int b = rest >> 2;
    int i = (ig << 6) + lane;

    size_t hrow = ((size_t)b * H_ + h) * N_;
    float si = sbuf[hrow + i];
    const float* adjrow  = adj       + ((size_t)b * N_ + i) * N_;
    const float* maskrow = attn_mask + ((size_t)b * N_ + i) * N_;
    const float* trow    = tbuf + hrow;
    const float* fbase   = feats + hrow * FP_;

    float acc[FP_];
#pragma unroll
    for (int d = 0; d < FP_; ++d) acc[d] = 0.f;
    float l = 0.f, A = 0.f, nz = 0.f;

    int j0 = jc * JSPAN_;
    for (int jb = 0; jb < JSPAN_; jb += 4) {
        int j = j0 + jb;
        float4 a4 = *(const float4*)(adjrow + j);
        float4 m4 = *(const float4*)(maskrow + j);
        float4 t4 = *(const float4*)(trow + j);       // lane-uniform (broadcast)
#pragma unroll
        for (int q = 0; q < 4; ++q) {
            float adjv  = ((const float*)&a4)[q];
            float maskv = ((const float*)&m4)[q];
            float tj    = ((const float*)&t4)[q];
            float dv = si + tj;
            dv = dv > 0.f ? dv : 0.2f * dv;           // LeakyReLU(0.2)
            dv += maskv;
            float e = __expf(dv);                     // bounded inputs: no max needed
            float p = e * adjv;
            l += e;
            A += p;
            nz += (p != 0.f ? 1.f : 0.f) - (adjv != 0.f ? 1.f : 0.f);
            const float4* fr = (const float4*)(fbase + (size_t)(j + q) * FP_); // uniform
#pragma unroll
            for (int k = 0; k < 8; ++k) {
                float4 fv = fr[k];
                acc[4 * k + 0] += p * fv.x;
                acc[4 * k + 1] += p * fv.y;
                acc[4 * k + 2] += p * fv.z;
                acc[4 * k + 3] += p * fv.w;
            }
        }
    }
    float* pr = part + ((hrow + i) * JC_ + jc) * PREC_;
#pragma unroll
    for (int d = 0; d < FP_; ++d) pr[d] = acc[d];
    pr[32] = l; pr[33] = A; pr[34] = nz;
}

// ---------------------------------------------------------------- kernel 3
// Combine j-chunk partials, bias + batchnorm(inference) + relu, per-(b,i) loss partials.
__global__ __launch_bounds__(128) void final_kernel(
    const float* __restrict__ part, const float* __restrict__ bias,
    const float* __restrict__ gamma, const float* __restrict__ beta,
    const float* __restrict__ mmean, const float* __restrict__ mvar,
    float2* __restrict__ lossbuf, float* __restrict__ out)
{
    int bn = blockIdx.x;
    int b = bn >> 11, i = bn & (N_ - 1);
    int t = threadIdx.x, h = t >> 5, d = t & 31;
    const float* pr = part + (((size_t)b * H_ + h) * N_ + i) * JC_ * PREC_;
    float acc = 0.f, l = 0.f, A = 0.f, nz = 0.f;
#pragma unroll
    for (int c = 0; c < JC_; ++c) {
        acc += pr[c * PREC_ + d];
        l   += pr[c * PREC_ + 32];
        A   += pr[c * PREC_ + 33];
        nz  += pr[c * PREC_ + 34];
    }
    int cidx = h * FP_ + d;
    float node = acc / l + bias[cidx];
    float o = (node - mmean[cidx]) * rsqrtf(mvar[cidx] + 1e-3f) * gamma[cidx] + beta[cidx];
    out[(size_t)bn * C_ + cidx] = o > 0.f ? o : 0.f;

    __shared__ float lu[H_], le[H_];
    if (d == 0) { lu[h] = nz; le[h] = A / l; }
    __syncthreads();
    if (t == 0) {
        float u = 0.f, e = 0.f;
#pragma unroll
        for (int hh = 0; hh < H_; ++hh) { u += lu[hh]; e += le[hh]; }
        lossbuf[bn] = make_float2(u * (1.f / N_), e * (1.f / N_));
    }
}

// ---------------------------------------------------------------- kernel 4
__global__ __launch_bounds__(256) void loss_kernel(
    const float2* __restrict__ lossbuf, float* __restrict__ out)
{
    float u = 0.f, e = 0.f;
    for (int idx = threadIdx.x; idx < B_ * N_; idx += 256) {
        float2 v = lossbuf[idx];
        u += v.x; e += v.y;
    }
    __shared__ float su[256], se[256];
    su[threadIdx.x] = u; se[threadIdx.x] = e;
    __syncthreads();
    for (int o = 128; o; o >>= 1) {
        if (threadIdx.x < o) {
            su[threadIdx.x] += su[threadIdx.x + o];
            se[threadIdx.x] += se[threadIdx.x + o];
        }
        __syncthreads();
    }
    if (threadIdx.x == 0) {
        out[(size_t)B_ * N_ * C_]     = su[0];  // uloss
        out[(size_t)B_ * N_ * C_ + 1] = se[0];  // eloss
    }
}

// ---------------------------------------------------------------- launch
extern "C" void kernel_launch(void* const* d_in, const int* in_sizes, int n_in,
                              void* d_out, int out_size, void* d_ws, size_t ws_size,
                              hipStream_t stream)
{
    const float* x         = (const float*)d_in[0];
    const float* adj       = (const float*)d_in[1];
    const float* attn_mask = (const float*)d_in[2];
    const float* W         = (const float*)d_in[3];
    const float* a_self    = (const float*)d_in[4];
    const float* a_neigh   = (const float*)d_in[5];
    const float* bias      = (const float*)d_in[6];
    const float* gamma     = (const float*)d_in[7];
    const float* beta      = (const float*)d_in[8];
    const float* mmean     = (const float*)d_in[9];
    const float* mvar      = (const float*)d_in[10];
    float* out = (float*)d_out;

    float* ws    = (float*)d_ws;
    float* feats = ws;                                              // 1,048,576 f
    float* sbuf  = feats + (size_t)B_ * H_ * N_ * FP_;              //    32,768 f
    float* tbuf  = sbuf  + (size_t)B_ * H_ * N_;                    //    32,768 f
    float* part  = tbuf  + (size_t)B_ * H_ * N_;                    // 9,437,184 f
    float* lossb = part  + (size_t)B_ * H_ * N_ * JC_ * PREC_;      //    16,384 f

    hipLaunchKernelGGL(prep_kernel, dim3(B_ * N_), dim3(128), 0, stream,
                       x, W, a_self, a_neigh, feats, sbuf, tbuf);
    hipLaunchKernelGGL(attn_kernel, dim3(B_ * H_ * (N_ / 64) * JC_ / 4), dim3(256), 0, stream,
                       adj, attn_mask, feats, sbuf, tbuf, part);
    hipLaunchKernelGGL(final_kernel, dim3(B_ * N_), dim3(128), 0, stream,
                       part, bias, gamma, beta, mmean, mvar, (float2*)lossb, out);
    hipLaunchKernelGGL(loss_kernel, dim3(1), dim3(256), 0, stream,
                       (const float2*)lossb, out);
}

// Round 2
// 462.411 us; speedup vs baseline: 1.1781x; 1.1781x over previous
//
#include <hip/hip_runtime.h>

// GraphAttention fused forward for MI355X (gfx950).
// B=4, N=2048, F=64, FP=32, H=4.  Output: [B,N,H*FP] f32 ++ uloss ++ eloss.

#define B_ 4
#define N_ 2048
#define F_ 64
#define FP_ 32
#define H_ 4
#define C_ (H_ * FP_)          // 128
#define JC_ 8                  // j-chunks per i-row
#define JSPAN_ (N_ / JC_)      // 256
#define NPLANE_ 35             // 32 acc + l + A + nz, stored plane-major [plane][i]
#define LDSP_ 65               // padded LDS row (2-way bank alias = free)

// ---------------------------------------------------------------- kernel 1
// feats[b,h,n,d] = sum_f x[b,n,f] * W[h,f,d];  s = feats . a_self; t = feats . a_neigh
__global__ __launch_bounds__(128) void prep_kernel(
    const float* __restrict__ x, const float* __restrict__ W,
    const float* __restrict__ a_self, const float* __restrict__ a_neigh,
    float* __restrict__ feats, float* __restrict__ sbuf, float* __restrict__ tbuf)
{
    int bn = blockIdx.x;              // b*N + n
    __shared__ float xs[F_];
    int t = threadIdx.x;
    if (t < F_) xs[t] = x[(size_t)bn * F_ + t];
    __syncthreads();
    int h = t >> 5, d = t & 31;
    const float* Wh = W + (size_t)h * F_ * FP_ + d;
    float acc = 0.f;
#pragma unroll
    for (int f = 0; f < F_; ++f) acc += xs[f] * Wh[(size_t)f * FP_];
    int b = bn >> 11, n = bn & (N_ - 1);
    size_t row = ((size_t)b * H_ + h) * N_ + n;
    feats[row * FP_ + d] = acc;
    float sv = acc * a_self[h * FP_ + d];
    float tv = acc * a_neigh[h * FP_ + d];
#pragma unroll
    for (int o = 16; o; o >>= 1) {
        sv += __shfl_down(sv, o, 32);
        tv += __shfl_down(tv, o, 32);
    }
    if (d == 0) { sbuf[row] = sv; tbuf[row] = tv; }
}

// ---------------------------------------------------------------- kernel 2
// Block = (b, 64-row i-group, j-chunk); 4 waves = 4 heads (adj/mask fetched ONCE).
// Stage adj/mask 64x64 tile into LDS coalesced; compute with lanes = i.
__global__ __launch_bounds__(256, 4) void attn_kernel(
    const float* __restrict__ adj, const float* __restrict__ attn_mask,
    const float* __restrict__ feats, const float* __restrict__ sbuf,
    const float* __restrict__ tbuf, float* __restrict__ part)
{
    __shared__ float lds_adj[64 * LDSP_];
    __shared__ float lds_msk[64 * LDSP_];
    __shared__ float lds_t[H_ * 64];

    int blk = blockIdx.x;             // b*32*JC + ig*JC + jc? -> decode bits
    int jc = blk & (JC_ - 1);
    int ig = (blk >> 3) & 31;
    int b  = blk >> 8;
    int t = threadIdx.x;
    int h = t >> 6, lane = t & 63;
    int i0 = ig << 6;

    size_t hrow = ((size_t)b * H_ + h) * N_;
    float si = sbuf[hrow + i0 + lane];
    const float* frow    = feats + hrow * FP_;
    const float* adjbase = adj       + ((size_t)b * N_ + i0) * N_;
    const float* mskbase = attn_mask + ((size_t)b * N_ + i0) * N_;

    float acc[FP_];
#pragma unroll
    for (int d = 0; d < FP_; ++d) acc[d] = 0.f;
    float l = 0.f, A = 0.f, nz = 0.f;

    for (int sub = 0; sub < JSPAN_ / 64; ++sub) {
        int j0 = jc * JSPAN_ + sub * 64;
        __syncthreads();              // previous phase-B readers done
        // ---- stage: wave h loads rows h, h+4, ... (lane = j, fully coalesced)
#pragma unroll
        for (int p = 0; p < 16; ++p) {
            int i = h + H_ * p;
            lds_adj[i * LDSP_ + lane] = adjbase[(size_t)i * N_ + j0 + lane];
            lds_msk[i * LDSP_ + lane] = mskbase[(size_t)i * N_ + j0 + lane];
        }
        lds_t[h * 64 + lane] = tbuf[hrow + j0 + lane];
        __syncthreads();
        // ---- compute: lanes = i, j loop wave-uniform
#pragma unroll 2
        for (int j = 0; j < 64; ++j) {
            float adjv = lds_adj[lane * LDSP_ + j];
            float mv   = lds_msk[lane * LDSP_ + j];
            float tj   = lds_t[h * 64 + j];        // broadcast
            float dv = si + tj;
            dv = dv > 0.f ? dv : 0.2f * dv;        // LeakyReLU(0.2)
            dv += mv;
            float e = __expf(dv);                  // bounded inputs: no max needed
            float p = e * adjv;
            l += e; A += p;
            nz += (p != 0.f ? 1.f : 0.f) - (adjv != 0.f ? 1.f : 0.f);
            const float4* fr = (const float4*)(frow + (size_t)(j0 + j) * FP_); // uniform
#pragma unroll
            for (int k = 0; k < 8; ++k) {
                float4 fv = fr[k];
                acc[4 * k + 0] += p * fv.x;
                acc[4 * k + 1] += p * fv.y;
                acc[4 * k + 2] += p * fv.z;
                acc[4 * k + 3] += p * fv.w;
            }
        }
    }
    // ---- partials, plane-major: part[((b,h,jc)*NPLANE + plane)*N + i] (coalesced)
    float* pl = part + (((size_t)(b * H_ + h) * JC_ + jc) * NPLANE_) * N_ + i0 + lane;
#pragma unroll
    for (int d = 0; d < FP_; ++d) pl[(size_t)d * N_] = acc[d];
    pl[(size_t)32 * N_] = l;
    pl[(size_t)33 * N_] = A;
    pl[(size_t)34 * N_] = nz;
}

// ---------------------------------------------------------------- kernel 3
// Block = (b, i-group). Combine jc partials (coalesced), BN+ReLU, LDS transpose,
// coalesced float4 out stores; per-(b,ig,h) loss partials via wave reduce.
__global__ __launch_bounds__(256) void final_kernel(
    const float* __restrict__ part, const float* __restrict__ bias,
    const float* __restrict__ gamma, const float* __restrict__ beta,
    const float* __restrict__ mmean, const float* __restrict__ mvar,
    float2* __restrict__ lossbuf, float* __restrict__ out)
{
    __shared__ float lds_out[64 * 129];
    int blk = blockIdx.x;             // b*32 + ig
    int b = blk >> 5, ig = blk & 31;
    int t = threadIdx.x, h = t >> 6, lane = t & 63;
    int i0 = ig << 6;

    const float* pb = part + ((size_t)(b * H_ + h) * JC_) * NPLANE_ * N_ + i0 + lane;
    float vals[FP_];
#pragma unroll
    for (int d = 0; d < FP_; ++d) vals[d] = 0.f;
    float l = 0.f, A = 0.f, nz = 0.f;
#pragma unroll
    for (int c = 0; c < JC_; ++c) {
        const float* pc = pb + (size_t)c * NPLANE_ * N_;
#pragma unroll
        for (int d = 0; d < FP_; ++d) vals[d] += pc[(size_t)d * N_];
        l  += pc[(size_t)32 * N_];
        A  += pc[(size_t)33 * N_];
        nz += pc[(size_t)34 * N_];
    }
    float inv = 1.f / l;
#pragma unroll
    for (int d = 0; d < FP_; ++d) {
        int c = h * FP_ + d;
        float node = vals[d] * inv + bias[c];
        float o = (node - mmean[c]) * rsqrtf(mvar[c] + 1e-3f) * gamma[c] + beta[c];
        lds_out[lane * 129 + c] = o > 0.f ? o : 0.f;
    }
    // loss partials: sum over the 64 i-rows of this wave's head
    float u = nz, e = A * inv;
#pragma unroll
    for (int o = 32; o; o >>= 1) { u += __shfl_down(u, o); e += __shfl_down(e, o); }
    if (lane == 0) lossbuf[(size_t)(b * 32 + ig) * H_ + h] = make_float2(u, e);
    __syncthreads();
    // coalesced out: wave h writes rows h*16..h*16+15, 2 rows per pass
#pragma unroll
    for (int p = 0; p < 8; ++p) {
        int r  = h * 16 + p * 2 + (lane >> 5);
        int c4 = (lane & 31) * 4;
        float4 v;
        v.x = lds_out[r * 129 + c4 + 0];
        v.y = lds_out[r * 129 + c4 + 1];
        v.z = lds_out[r * 129 + c4 + 2];
        v.w = lds_out[r * 129 + c4 + 3];
        *(float4*)(out + ((size_t)(b * N_ + i0 + r)) * C_ + c4) = v;
    }
}

// ---------------------------------------------------------------- kernel 4
__global__ __launch_bounds__(256) void loss_kernel(
    const float2* __restrict__ lossbuf, float* __restrict__ out)
{
    float u = 0.f, e = 0.f;
    for (int idx = threadIdx.x; idx < B_ * 32 * H_; idx += 256) {
        float2 v = lossbuf[idx];
        u += v.x; e += v.y;
    }
    __shared__ float su[256], se[256];
    su[threadIdx.x] = u; se[threadIdx.x] = e;
    __syncthreads();
    for (int o = 128; o; o >>= 1) {
        if (threadIdx.x < o) {
            su[threadIdx.x] += su[threadIdx.x + o];
            se[threadIdx.x] += se[threadIdx.x + o];
        }
        __syncthreads();
    }
    if (threadIdx.x == 0) {
        out[(size_t)B_ * N_ * C_]     = su[0] * (1.f / N_);  // uloss
        out[(size_t)B_ * N_ * C_ + 1] = se[0] * (1.f / N_);  // eloss
    }
}

// ---------------------------------------------------------------- launch
extern "C" void kernel_launch(void* const* d_in, const int* in_sizes, int n_in,
                              void* d_out, int out_size, void* d_ws, size_t ws_size,
                              hipStream_t stream)
{
    const float* x         = (const float*)d_in[0];
    const float* adj       = (const float*)d_in[1];
    const float* attn_mask = (const float*)d_in[2];
    const float* W         = (const float*)d_in[3];
    const float* a_self    = (const float*)d_in[4];
    const float* a_neigh   = (const float*)d_in[5];
    const float* bias      = (const float*)d_in[6];
    const float* gamma     = (const float*)d_in[7];
    const float* beta      = (const float*)d_in[8];
    const float* mmean     = (const float*)d_in[9];
    const float* mvar      = (const float*)d_in[10];
    float* out = (float*)d_out;

    float* ws    = (float*)d_ws;
    float* feats = ws;                                              // 1,048,576 f
    float* sbuf  = feats + (size_t)B_ * H_ * N_ * FP_;              //    32,768 f
    float* tbuf  = sbuf  + (size_t)B_ * H_ * N_;                    //    32,768 f
    float* part  = tbuf  + (size_t)B_ * H_ * N_;                    // 9,175,040 f
    float* lossb = part  + (size_t)B_ * H_ * JC_ * NPLANE_ * N_;    //     1,024 f

    hipLaunchKernelGGL(prep_kernel, dim3(B_ * N_), dim3(128), 0, stream,
                       x, W, a_self, a_neigh, feats, sbuf, tbuf);
    hipLaunchKernelGGL(attn_kernel, dim3(B_ * 32 * JC_), dim3(256), 0, stream,
                       adj, attn_mask, feats, sbuf, tbuf, part);
    hipLaunchKernelGGL(final_kernel, dim3(B_ * 32), dim3(256), 0, stream,
                       part, bias, gamma, beta, mmean, mvar, (float2*)lossb, out);
    hipLaunchKernelGGL(loss_kernel, dim3(1), dim3(256), 0, stream,
                       (const float2*)lossb, out);
}

// Round 3
// 304.486 us; speedup vs baseline: 1.7892x; 1.5187x over previous
//
#include <hip/hip_runtime.h>

// GraphAttention fused forward for MI355X (gfx950).
// B=4, N=2048, F=64, FP=32, H=4.  Output: [B,N,H*FP] f32 ++ uloss ++ eloss.

#define B_ 4
#define N_ 2048
#define F_ 64
#define FP_ 32
#define H_ 4
#define C_ (H_ * FP_)          // 128
#define JC_ 8                  // j-chunks per i-row
#define JSPAN_ (N_ / JC_)      // 256
#define JT_ 32                 // j sub-tile staged in LDS
#define NPLANE_ 35             // 32 acc + l + A + nz, plane-major [plane][i]

// ---------------------------------------------------------------- kernel 1
// Block = 32 n-rows. W column in registers, x tile in LDS. FMA-bound.
__global__ __launch_bounds__(256) void prep_kernel(
    const float* __restrict__ x, const float* __restrict__ W,
    const float* __restrict__ a_self, const float* __restrict__ a_neigh,
    float* __restrict__ feats, float* __restrict__ sbuf, float* __restrict__ tbuf)
{
    __shared__ float xs[32 * F_];
    int t = threadIdx.x;
    int blk = blockIdx.x;              // b*64 + nb
    int b = blk >> 6, nb = blk & 63;
    int n0 = nb << 5;
    const float* xbase = x + ((size_t)b * N_ + n0) * F_;
#pragma unroll
    for (int q = 0; q < 2; ++q) {
        int idx = (q * 256 + t) * 4;
        *(float4*)&xs[idx] = *(const float4*)(xbase + idx);
    }
    int d = t & 31, h = (t >> 5) & 3, ns = t >> 7;
    float w[F_];
    const float* Wp = W + (size_t)h * F_ * FP_ + d;
#pragma unroll
    for (int f = 0; f < F_; ++f) w[f] = Wp[(size_t)f * FP_];
    float as = a_self[h * FP_ + d], an = a_neigh[h * FP_ + d];
    __syncthreads();
    for (int nn = 0; nn < 16; ++nn) {
        int n = ns * 16 + nn;
        float acc = 0.f;
#pragma unroll
        for (int f = 0; f < F_; ++f) acc += xs[n * F_ + f] * w[f];
        size_t row = ((size_t)b * H_ + h) * N_ + n0 + n;
        feats[row * FP_ + d] = acc;
        float sv = acc * as, tv = acc * an;
#pragma unroll
        for (int o = 16; o; o >>= 1) {
            sv += __shfl_down(sv, o, 32);
            tv += __shfl_down(tv, o, 32);
        }
        if (d == 0) { sbuf[row] = sv; tbuf[row] = tv; }
    }
}

// ---------------------------------------------------------------- kernel 2
// Block = (b, 128-row i-group, j-chunk); 4 waves = 4 heads.
// adj/mask/feats/t all staged in LDS per 32-j sub-tile; 2 i-rows per lane.
__global__ __launch_bounds__(256, 2) void attn_kernel(
    const float* __restrict__ adj, const float* __restrict__ attn_mask,
    const float* __restrict__ feats, const float* __restrict__ sbuf,
    const float* __restrict__ tbuf, float* __restrict__ part)
{
    __shared__ float lds_adj[128 * 33];   // [r][j], pad 33 -> 2-way bank = free
    __shared__ float lds_msk[128 * 33];
    __shared__ float lds_F[H_ * JT_ * FP_];  // [h][j][d]
    __shared__ float lds_t[H_ * JT_];

    int blk = blockIdx.x;
    int jc = blk & (JC_ - 1);
    int ig = (blk >> 3) & 15;
    int b  = blk >> 7;
    int t = threadIdx.x;
    int h = t >> 6, lane = t & 63;
    int i0 = ig << 7;                     // 128 rows per block

    size_t hrow = ((size_t)b * H_ + h) * N_;
    float si0 = sbuf[hrow + i0 + lane];
    float si1 = sbuf[hrow + i0 + 64 + lane];
    const float* frow    = feats + hrow * FP_;
    const float* adjbase = adj       + ((size_t)b * N_ + i0) * N_;
    const float* mskbase = attn_mask + ((size_t)b * N_ + i0) * N_;

    float acc0[FP_], acc1[FP_];
#pragma unroll
    for (int d = 0; d < FP_; ++d) { acc0[d] = 0.f; acc1[d] = 0.f; }
    float l0 = 0.f, A0 = 0.f, nz0 = 0.f;
    float l1 = 0.f, A1 = 0.f, nz1 = 0.f;

    int jr = t & 31, rb = t >> 5;         // staging coords
    int jj = lane >> 3, d4 = (lane & 7) * 4;

    for (int sub = 0; sub < JSPAN_ / JT_; ++sub) {
        int j0 = jc * JSPAN_ + sub * JT_;
        __syncthreads();                  // previous compute done
#pragma unroll
        for (int p = 0; p < 16; ++p) {
            int r = rb + 8 * p;
            lds_adj[r * 33 + jr] = adjbase[(size_t)r * N_ + j0 + jr];
            lds_msk[r * 33 + jr] = mskbase[(size_t)r * N_ + j0 + jr];
        }
#pragma unroll
        for (int q = 0; q < 4; ++q) {
            int j = jj + 8 * q;
            *(float4*)&lds_F[(h * JT_ + j) * FP_ + d4] =
                *(const float4*)(frow + (size_t)(j0 + j) * FP_ + d4);
        }
        if (lane < JT_) lds_t[h * JT_ + lane] = tbuf[hrow + j0 + lane];
        __syncthreads();
#pragma unroll 4
        for (int j = 0; j < JT_; ++j) {
            float a0 = lds_adj[lane * 33 + j];
            float a1 = lds_adj[(lane + 64) * 33 + j];
            float m0 = lds_msk[lane * 33 + j];
            float m1 = lds_msk[(lane + 64) * 33 + j];
            float tj = lds_t[h * JT_ + j];                 // broadcast
            float dv0 = si0 + tj; dv0 = dv0 > 0.f ? dv0 : 0.2f * dv0; dv0 += m0;
            float dv1 = si1 + tj; dv1 = dv1 > 0.f ? dv1 : 0.2f * dv1; dv1 += m1;
            float e0 = __expf(dv0), e1 = __expf(dv1);      // bounded: no max needed
            float p0 = e0 * a0,  p1 = e1 * a1;
            l0 += e0; A0 += p0; l1 += e1; A1 += p1;
            nz0 += (p0 != 0.f ? 1.f : 0.f) - (a0 != 0.f ? 1.f : 0.f);
            nz1 += (p1 != 0.f ? 1.f : 0.f) - (a1 != 0.f ? 1.f : 0.f);
            const float4* fr = (const float4*)&lds_F[(h * JT_ + j) * FP_]; // uniform
#pragma unroll
            for (int k = 0; k < 8; ++k) {
                float4 fv = fr[k];
                acc0[4 * k + 0] += p0 * fv.x; acc1[4 * k + 0] += p1 * fv.x;
                acc0[4 * k + 1] += p0 * fv.y; acc1[4 * k + 1] += p1 * fv.y;
                acc0[4 * k + 2] += p0 * fv.z; acc1[4 * k + 2] += p1 * fv.z;
                acc0[4 * k + 3] += p0 * fv.w; acc1[4 * k + 3] += p1 * fv.w;
            }
        }
    }
    // partials, plane-major: part[((b,h,jc)*NPLANE + plane)*N + i] (coalesced)
    float* pl = part + (((size_t)(b * H_ + h) * JC_ + jc) * NPLANE_) * N_ + i0 + lane;
#pragma unroll
    for (int d = 0; d < FP_; ++d) {
        pl[(size_t)d * N_]      = acc0[d];
        pl[(size_t)d * N_ + 64] = acc1[d];
    }
    pl[(size_t)32 * N_] = l0;  pl[(size_t)32 * N_ + 64] = l1;
    pl[(size_t)33 * N_] = A0;  pl[(size_t)33 * N_ + 64] = A1;
    pl[(size_t)34 * N_] = nz0; pl[(size_t)34 * N_ + 64] = nz1;
}

// ---------------------------------------------------------------- kernel 3
// Block = (b, 64-row i-group). Combine jc partials (coalesced), BN+ReLU,
// LDS transpose, coalesced float4 out stores; loss partials via wave reduce.
__global__ __launch_bounds__(256) void final_kernel(
    const float* __restrict__ part, const float* __restrict__ bias,
    const float* __restrict__ gamma, const float* __restrict__ beta,
    const float* __restrict__ mmean, const float* __restrict__ mvar,
    float2* __restrict__ lossbuf, float* __restrict__ out)
{
    __shared__ float lds_out[64 * 129];
    int blk = blockIdx.x;             // b*32 + ig
    int b = blk >> 5, ig = blk & 31;
    int t = threadIdx.x, h = t >> 6, lane = t & 63;
    int i0 = ig << 6;

    const float* pb = part + ((size_t)(b * H_ + h) * JC_) * NPLANE_ * N_ + i0 + lane;
    float vals[FP_];
#pragma unroll
    for (int d = 0; d < FP_; ++d) vals[d] = 0.f;
    float l = 0.f, A = 0.f, nz = 0.f;
#pragma unroll
    for (int c = 0; c < JC_; ++c) {
        const float* pc = pb + (size_t)c * NPLANE_ * N_;
#pragma unroll
        for (int d = 0; d < FP_; ++d) vals[d] += pc[(size_t)d * N_];
        l  += pc[(size_t)32 * N_];
        A  += pc[(size_t)33 * N_];
        nz += pc[(size_t)34 * N_];
    }
    float inv = 1.f / l;
#pragma unroll
    for (int d = 0; d < FP_; ++d) {
        int c = h * FP_ + d;
        float node = vals[d] * inv + bias[c];
        float o = (node - mmean[c]) * rsqrtf(mvar[c] + 1e-3f) * gamma[c] + beta[c];
        lds_out[lane * 129 + c] = o > 0.f ? o : 0.f;
    }
    float u = nz, e = A * inv;
#pragma unroll
    for (int o = 32; o; o >>= 1) { u += __shfl_down(u, o); e += __shfl_down(e, o); }
    if (lane == 0) lossbuf[(size_t)(b * 32 + ig) * H_ + h] = make_float2(u, e);
    __syncthreads();
#pragma unroll
    for (int p = 0; p < 8; ++p) {
        int r  = h * 16 + p * 2 + (lane >> 5);
        int c4 = (lane & 31) * 4;
        float4 v;
        v.x = lds_out[r * 129 + c4 + 0];
        v.y = lds_out[r * 129 + c4 + 1];
        v.z = lds_out[r * 129 + c4 + 2];
        v.w = lds_out[r * 129 + c4 + 3];
        *(float4*)(out + ((size_t)(b * N_ + i0 + r)) * C_ + c4) = v;
    }
}

// ---------------------------------------------------------------- kernel 4
__global__ __launch_bounds__(256) void loss_kernel(
    const float2* __restrict__ lossbuf, float* __restrict__ out)
{
    float u = 0.f, e = 0.f;
    for (int idx = threadIdx.x; idx < B_ * 32 * H_; idx += 256) {
        float2 v = lossbuf[idx];
        u += v.x; e += v.y;
    }
    __shared__ float su[256], se[256];
    su[threadIdx.x] = u; se[threadIdx.x] = e;
    __syncthreads();
    for (int o = 128; o; o >>= 1) {
        if (threadIdx.x < o) {
            su[threadIdx.x] += su[threadIdx.x + o];
            se[threadIdx.x] += se[threadIdx.x + o];
        }
        __syncthreads();
    }
    if (threadIdx.x == 0) {
        out[(size_t)B_ * N_ * C_]     = su[0] * (1.f / N_);  // uloss
        out[(size_t)B_ * N_ * C_ + 1] = se[0] * (1.f / N_);  // eloss
    }
}

// ---------------------------------------------------------------- launch
extern "C" void kernel_launch(void* const* d_in, const int* in_sizes, int n_in,
                              void* d_out, int out_size, void* d_ws, size_t ws_size,
                              hipStream_t stream)
{
    const float* x         = (const float*)d_in[0];
    const float* adj       = (const float*)d_in[1];
    const float* attn_mask = (const float*)d_in[2];
    const float* W         = (const float*)d_in[3];
    const float* a_self    = (const float*)d_in[4];
    const float* a_neigh   = (const float*)d_in[5];
    const float* bias      = (const float*)d_in[6];
    const float* gamma     = (const float*)d_in[7];
    const float* beta      = (const float*)d_in[8];
    const float* mmean     = (const float*)d_in[9];
    const float* mvar      = (const float*)d_in[10];
    float* out = (float*)d_out;

    float* ws    = (float*)d_ws;
    float* feats = ws;                                              // 1,048,576 f
    float* sbuf  = feats + (size_t)B_ * H_ * N_ * FP_;              //    32,768 f
    float* tbuf  = sbuf  + (size_t)B_ * H_ * N_;                    //    32,768 f
    float* part  = tbuf  + (size_t)B_ * H_ * N_;                    // 9,175,040 f
    float* lossb = part  + (size_t)B_ * H_ * JC_ * NPLANE_ * N_;    //     1,024 f

    hipLaunchKernelGGL(prep_kernel, dim3(B_ * 64), dim3(256), 0, stream,
                       x, W, a_self, a_neigh, feats, sbuf, tbuf);
    hipLaunchKernelGGL(attn_kernel, dim3(B_ * 16 * JC_), dim3(256), 0, stream,
                       adj, attn_mask, feats, sbuf, tbuf, part);
    hipLaunchKernelGGL(final_kernel, dim3(B_ * 32), dim3(256), 0, stream,
                       part, bias, gamma, beta, mmean, mvar, (float2*)lossb, out);
    hipLaunchKernelGGL(loss_kernel, dim3(1), dim3(256), 0, stream,
                       (const float2*)lossb, out);
}

// Round 4
// 209.558 us; speedup vs baseline: 2.5997x; 1.4530x over previous
//
#include <hip/hip_runtime.h>

// GraphAttention fused forward for MI355X (gfx950), MFMA-based.
// B=4, N=2048, F=64, FP=32, H=4.  Output: [B,N,H*FP] f32 ++ uloss ++ eloss.

#define B_ 4
#define N_ 2048
#define F_ 64
#define FP_ 32
#define H_ 4
#define C_ 128
#define IT_ 16                 // i-rows per attn block
#define ITILES_ (N_ / IT_)     // 128
#define JCA_ 2                 // j-chunks (partial accumulation)
#define JSPANA_ (N_ / JCA_)    // 1024
#define JST_ 128               // j staging subtile
#define APAD_ 132              // padded LDS row (fp32): (4r+j)%32 -> 2-way, 16B-aligned

typedef __attribute__((ext_vector_type(8))) short short8v;   // 8 bf16 = 4 VGPRs
typedef __attribute__((ext_vector_type(4))) float f32x4;     // MFMA C/D

__device__ __forceinline__ unsigned short f2bf(float f) {    // RNE fp32->bf16
    unsigned u = __float_as_uint(f);
    u += 0x7fffu + ((u >> 16) & 1u);
    return (unsigned short)(u >> 16);
}

// ---------------------------------------------------------------- kernel 1
// feats = x@W per head via MFMA; writes featsT bf16 [b][h][d][n] + s,t fp32.
// Block = (b, 64-row n-tile); 4 waves = 4 heads.
__global__ __launch_bounds__(256) void prep_kernel(
    const float* __restrict__ x, const float* __restrict__ W,
    const float* __restrict__ a_self, const float* __restrict__ a_neigh,
    unsigned short* __restrict__ featsT, float* __restrict__ sbuf,
    float* __restrict__ tbuf)
{
    int blk = blockIdx.x;              // b*32 + nt
    int b = blk >> 5, nt = blk & 31;
    int n0 = nt << 6;
    int t = threadIdx.x, h = t >> 6, lane = t & 63;
    int quad = lane >> 4, col = lane & 15;

    // B-frags: W[h][f][d] bf16; k=f packed as quad*8+e (same mapping as A)
    short8v bw[2][2];
    const float* Wh = W + (size_t)h * F_ * FP_;
#pragma unroll
    for (int kc = 0; kc < 2; ++kc)
#pragma unroll
        for (int dt = 0; dt < 2; ++dt)
#pragma unroll
            for (int e = 0; e < 8; ++e) {
                int f = kc * 32 + quad * 8 + e;
                bw[kc][dt][e] = (short)f2bf(Wh[f * FP_ + dt * 16 + col]);
            }
    float as0 = a_self[h * FP_ + col],  as1 = a_self[h * FP_ + 16 + col];
    float an0 = a_neigh[h * FP_ + col], an1 = a_neigh[h * FP_ + 16 + col];
    size_t hrow = ((size_t)b * H_ + h) * N_;
    size_t ftb  = ((size_t)b * H_ + h) * FP_;

    for (int ms = 0; ms < 4; ++ms) {
        int row = n0 + ms * 16 + col;          // A row m = lane&15
        const float* xr = x + ((size_t)b * N_ + row) * F_;
        f32x4 acc0 = {0.f, 0.f, 0.f, 0.f}, acc1 = {0.f, 0.f, 0.f, 0.f};
#pragma unroll
        for (int kc = 0; kc < 2; ++kc) {
            float4 x0 = *(const float4*)(xr + kc * 32 + quad * 8);
            float4 x1 = *(const float4*)(xr + kc * 32 + quad * 8 + 4);
            short8v av;
            av[0] = (short)f2bf(x0.x); av[1] = (short)f2bf(x0.y);
            av[2] = (short)f2bf(x0.z); av[3] = (short)f2bf(x0.w);
            av[4] = (short)f2bf(x1.x); av[5] = (short)f2bf(x1.y);
            av[6] = (short)f2bf(x1.z); av[7] = (short)f2bf(x1.w);
            acc0 = __builtin_amdgcn_mfma_f32_16x16x32_bf16(av, bw[kc][0], acc0, 0, 0, 0);
            acc1 = __builtin_amdgcn_mfma_f32_16x16x32_bf16(av, bw[kc][1], acc1, 0, 0, 0);
        }
        // C layout: row = quad*4+rr, col = lane&15 (verified m89/m91)
        {
            ushort4 v0, v1;
            v0.x = f2bf(acc0[0]); v0.y = f2bf(acc0[1]);
            v0.z = f2bf(acc0[2]); v0.w = f2bf(acc0[3]);
            v1.x = f2bf(acc1[0]); v1.y = f2bf(acc1[1]);
            v1.z = f2bf(acc1[2]); v1.w = f2bf(acc1[3]);
            size_t nidx = (size_t)n0 + ms * 16 + quad * 4;
            *(ushort4*)(featsT + (ftb + col) * N_ + nidx)      = v0;
            *(ushort4*)(featsT + (ftb + 16 + col) * N_ + nidx) = v1;
        }
#pragma unroll
        for (int rr = 0; rr < 4; ++rr) {
            float sv = acc0[rr] * as0 + acc1[rr] * as1;
            float tv = acc0[rr] * an0 + acc1[rr] * an1;
#pragma unroll
            for (int off = 8; off; off >>= 1) {
                sv += __shfl_down(sv, off);
                tv += __shfl_down(tv, off);
            }
            if (col == 0) {
                int n = n0 + ms * 16 + quad * 4 + rr;
                sbuf[hrow + n] = sv;
                tbuf[hrow + n] = tv;
            }
        }
    }
}

// ---------------------------------------------------------------- kernel 2
// Block = (b, 16-row i-tile, jc); 4 waves = 4 heads. adj/mask via LDS (once),
// P built in-register in MFMA A-layout, PV via mfma 16x16x32 bf16.
__global__ __launch_bounds__(256) void attn_kernel(
    const float* __restrict__ adj, const float* __restrict__ msk,
    const unsigned short* __restrict__ featsT,
    const float* __restrict__ sbuf, const float* __restrict__ tbuf,
    float* __restrict__ part, float* __restrict__ lpart)
{
    __shared__ float lds_adj[IT_ * APAD_];
    __shared__ float lds_msk[IT_ * APAD_];

    int blk = blockIdx.x;
    int jc = blk & (JCA_ - 1);
    int it = (blk >> 1) & (ITILES_ - 1);
    int b  = blk >> 8;
    int t = threadIdx.x, h = t >> 6, lane = t & 63;
    int quad = lane >> 4, r = lane & 15;
    int i0 = it * IT_;
    int jbase = jc * JSPANA_;

    size_t hrow = ((size_t)b * H_ + h) * N_;
    float si = sbuf[hrow + i0 + r];
    const float* trow = tbuf + hrow + jbase;
    const unsigned short* ft0 = featsT + (((size_t)b * H_ + h) * FP_ + r) * N_ + jbase;
    const unsigned short* ft1 = ft0 + (size_t)16 * N_;
    const float* adjb = adj + ((size_t)b * N_ + i0) * N_ + jbase;
    const float* mskb = msk + ((size_t)b * N_ + i0) * N_ + jbase;

    int srow = t >> 4, sj = (t & 15) * 8;

    f32x4 acc0 = {0.f, 0.f, 0.f, 0.f}, acc1 = {0.f, 0.f, 0.f, 0.f};
    float l = 0.f, A = 0.f, nz = 0.f;

    for (int st = 0; st < JSPANA_ / JST_; ++st) {
        int j0 = st * JST_;
        __syncthreads();
        {   // stage 16 x 128 adj+mask, coalesced
            const float* ga = adjb + (size_t)srow * N_ + j0 + sj;
            const float* gm = mskb + (size_t)srow * N_ + j0 + sj;
            *(float4*)&lds_adj[srow * APAD_ + sj]     = *(const float4*)ga;
            *(float4*)&lds_adj[srow * APAD_ + sj + 4] = *(const float4*)(ga + 4);
            *(float4*)&lds_msk[srow * APAD_ + sj]     = *(const float4*)gm;
            *(float4*)&lds_msk[srow * APAD_ + sj + 4] = *(const float4*)(gm + 4);
        }
        __syncthreads();
#pragma unroll
        for (int kc = 0; kc < JST_ / 32; ++kc) {
            int jt = kc * 32 + quad * 8;      // j within subtile
            int jl = j0 + jt;                 // j within span
            float4 a0 = *(const float4*)&lds_adj[r * APAD_ + jt];
            float4 a1 = *(const float4*)&lds_adj[r * APAD_ + jt + 4];
            float4 m0 = *(const float4*)&lds_msk[r * APAD_ + jt];
            float4 m1 = *(const float4*)&lds_msk[r * APAD_ + jt + 4];
            float4 t0 = *(const float4*)(trow + jl);
            float4 t1 = *(const float4*)(trow + jl + 4);
            short8v bv0 = *(const short8v*)(ft0 + jl);
            short8v bv1 = *(const short8v*)(ft1 + jl);
            float av[8] = {a0.x, a0.y, a0.z, a0.w, a1.x, a1.y, a1.z, a1.w};
            float mv[8] = {m0.x, m0.y, m0.z, m0.w, m1.x, m1.y, m1.z, m1.w};
            float tv[8] = {t0.x, t0.y, t0.z, t0.w, t1.x, t1.y, t1.z, t1.w};
            short8v ap;
#pragma unroll
            for (int q = 0; q < 8; ++q) {
                float dv = si + tv[q];
                dv = fmaxf(dv, 0.2f * dv);            // LeakyReLU(0.2)
                dv += mv[q];
                float e = __expf(dv);                 // bounded: no max-subtract
                float p = e * av[q];
                l += e; A += p;
                nz += (av[q] == 0.f ? 1.f : 0.f) - (p == 0.f ? 1.f : 0.f);
                ap[q] = (short)f2bf(p);
            }
            acc0 = __builtin_amdgcn_mfma_f32_16x16x32_bf16(ap, bv0, acc0, 0, 0, 0);
            acc1 = __builtin_amdgcn_mfma_f32_16x16x32_bf16(ap, bv1, acc1, 0, 0, 0);
        }
    }
    // row totals live in lanes 0-15 after folding the 4 k-group lanes
    l  += __shfl_down(l, 32);  l  += __shfl_down(l, 16);
    A  += __shfl_down(A, 32);  A  += __shfl_down(A, 16);
    nz += __shfl_down(nz, 32); nz += __shfl_down(nz, 16);

    size_t pb = ((((size_t)(b * H_ + h) * ITILES_ + it) * JCA_ + jc) * 2) * 256;
    *(f32x4*)&part[pb + lane * 4]       = acc0;   // raw C-frag, coalesced
    *(f32x4*)&part[pb + 256 + lane * 4] = acc1;
    if (lane < 16) {
        size_t lb = (((size_t)(b * H_ + h) * ITILES_ + it) * JCA_ + jc) * 48;
        lpart[lb + lane]      = l;
        lpart[lb + 16 + lane] = A;
        lpart[lb + 32 + lane] = nz;
    }
}

// ---------------------------------------------------------------- kernel 3
// Block = (b, i-tile). Merge jc partials (raw C-frag layout), /l, bias, BN,
// ReLU, LDS transpose, coalesced out; per-(block,h) loss partials.
__global__ __launch_bounds__(256) void final_kernel(
    const float* __restrict__ part, const float* __restrict__ lpart,
    const float* __restrict__ bias, const float* __restrict__ gamma,
    const float* __restrict__ beta, const float* __restrict__ mmean,
    const float* __restrict__ mvar, float2* __restrict__ lossbuf,
    float* __restrict__ out)
{
    __shared__ float ldsl[H_ * 16];
    __shared__ float ldso[IT_ * 132];
    int blk = blockIdx.x;              // b*128 + it
    int b = blk >> 7, it = blk & 127;
    int t = threadIdx.x, h = t >> 6, lane = t & 63;
    int quad = lane >> 4, col = lane & 15;

    size_t pb = (((size_t)(b * H_ + h) * ITILES_ + it) * JCA_) * 512;
    f32x4 C0 = *(const f32x4*)&part[pb + lane * 4];
    f32x4 C1 = *(const f32x4*)&part[pb + 256 + lane * 4];
    C0 += *(const f32x4*)&part[pb + 512 + lane * 4];
    C1 += *(const f32x4*)&part[pb + 768 + lane * 4];

    size_t lb = (((size_t)(b * H_ + h) * ITILES_ + it) * JCA_) * 48;
    if (lane < 16) {
        float lt  = lpart[lb + lane]      + lpart[lb + 48 + lane];
        float At  = lpart[lb + 16 + lane] + lpart[lb + 64 + lane];
        float nzt = lpart[lb + 32 + lane] + lpart[lb + 80 + lane];
        ldsl[h * 16 + lane] = lt;
        float u = nzt, e = At / lt;
#pragma unroll
        for (int off = 8; off; off >>= 1) { u += __shfl_down(u, off); e += __shfl_down(e, off); }
        if (lane == 0) lossbuf[blk * H_ + h] = make_float2(u, e);
    }
    __syncthreads();
#pragma unroll
    for (int dt = 0; dt < 2; ++dt) {
        int c = h * FP_ + dt * 16 + col;
        float sc = rsqrtf(mvar[c] + 1e-3f) * gamma[c];
        float sh = beta[c] - mmean[c] * sc;
        float bi = bias[c];
        f32x4 Cv = dt ? C1 : C0;
#pragma unroll
        for (int rr = 0; rr < 4; ++rr) {
            int row = quad * 4 + rr;
            float node = Cv[rr] / ldsl[h * 16 + row] + bi;
            float o = node * sc + sh;
            ldso[row * 132 + c] = o > 0.f ? o : 0.f;
        }
    }
    __syncthreads();
#pragma unroll
    for (int ps = 0; ps < 2; ++ps) {
        int row = ps * 8 + (t >> 5);
        int c4 = (t & 31) * 4;
        *(float4*)(out + ((size_t)b * N_ + it * IT_ + row) * C_ + c4) =
            *(const float4*)&ldso[row * 132 + c4];
    }
}

// ---------------------------------------------------------------- kernel 4
__global__ __launch_bounds__(256) void loss_kernel(
    const float2* __restrict__ lossbuf, float* __restrict__ out)
{
    float u = 0.f, e = 0.f;
    for (int idx = threadIdx.x; idx < B_ * ITILES_ * H_; idx += 256) {
        float2 v = lossbuf[idx];
        u += v.x; e += v.y;
    }
    __shared__ float su[256], se[256];
    su[threadIdx.x] = u; se[threadIdx.x] = e;
    __syncthreads();
    for (int o = 128; o; o >>= 1) {
        if (threadIdx.x < o) {
            su[threadIdx.x] += su[threadIdx.x + o];
            se[threadIdx.x] += se[threadIdx.x + o];
        }
        __syncthreads();
    }
    if (threadIdx.x == 0) {
        out[(size_t)B_ * N_ * C_]     = su[0] * (1.f / N_);  // uloss
        out[(size_t)B_ * N_ * C_ + 1] = se[0] * (1.f / N_);  // eloss
    }
}

// ---------------------------------------------------------------- launch
extern "C" void kernel_launch(void* const* d_in, const int* in_sizes, int n_in,
                              void* d_out, int out_size, void* d_ws, size_t ws_size,
                              hipStream_t stream)
{
    const float* x         = (const float*)d_in[0];
    const float* adj       = (const float*)d_in[1];
    const float* attn_mask = (const float*)d_in[2];
    const float* W         = (const float*)d_in[3];
    const float* a_self    = (const float*)d_in[4];
    const float* a_neigh   = (const float*)d_in[5];
    const float* bias      = (const float*)d_in[6];
    const float* gamma     = (const float*)d_in[7];
    const float* beta      = (const float*)d_in[8];
    const float* mmean     = (const float*)d_in[9];
    const float* mvar      = (const float*)d_in[10];
    float* out = (float*)d_out;

    float* ws = (float*)d_ws;
    unsigned short* featsT = (unsigned short*)ws;                    // 1,048,576 u16 = 524,288 f
    float* sbuf  = ws + 524288;                                      //    32,768 f
    float* tbuf  = sbuf + (size_t)B_ * H_ * N_;                      //    32,768 f
    float* part  = tbuf + (size_t)B_ * H_ * N_;                      // 2,097,152 f
    float* lpart = part + (size_t)B_ * H_ * ITILES_ * JCA_ * 2 * 256;//   196,608 f
    float* lossb = lpart + (size_t)B_ * H_ * ITILES_ * JCA_ * 48;    //     4,096 f

    hipLaunchKernelGGL(prep_kernel, dim3(B_ * 32), dim3(256), 0, stream,
                       x, W, a_self, a_neigh, featsT, sbuf, tbuf);
    hipLaunchKernelGGL(attn_kernel, dim3(B_ * ITILES_ * JCA_), dim3(256), 0, stream,
                       adj, attn_mask, featsT, sbuf, tbuf, part, lpart);
    hipLaunchKernelGGL(final_kernel, dim3(B_ * ITILES_), dim3(256), 0, stream,
                       part, lpart, bias, gamma, beta, mmean, mvar,
                       (float2*)lossb, out);
    hipLaunchKernelGGL(loss_kernel, dim3(1), dim3(256), 0, stream,
                       (const float2*)lossb, out);
}